// Round 8
// baseline (26758.646 us; speedup 1.0000x reference)
//
#include <hip/hip_runtime.h>
#include <hip/hip_bf16.h>

// bigRSNN: T=8192 strictly-serial spiking RNN.
//
// Phase 1 — SINGLE-XCD cluster, HEDGED coherence protocol.
// 256 selector blocks read HW_REG_XCC_ID (&7); each ranks itself on its XCD
// via an agent atomic counter; the block that brings one XCD's count to 32
// CAS-publishes that XCD as winner (pigeonhole over 256 blocks / 8 XCDs, all
// co-resident at 1 block/CU). Winner's ranks 0..31 are the workers; everyone
// else exits.
// Exchange per step t: block 'me' publishes its 32 spike bits as a tagged
// 8-B flag {(t+1)<<16|lo16,(t+1)<<16|hi16} into every consumer's private
// sector via BOTH an sc0 store (updates the shared home-XCD L2 -> fast
// intra-XCD visibility) and an agent-scope atomic store (LLC-visible ->
// fallback can always succeed; same value, so any ordering is benign).
// Consumers poll their own 32x8B sector: up to 6 sc0 (L2) spins, then
// permanent agent-scope atomic loads -- no spin can hang regardless of
// sc0 semantics. No barriers in the step loop; RING=4 slots; tag
// monotonicity + cross-block dependency chain make slot reuse safe.
// Phase 2: readout GEMM over the tagged raster + 10 IIR scans + head mean.

constexpr int T_STEPS = 8192;
constexpr int IN_DIM  = 192;
constexpr int H_DIM   = 1024;
constexpr int NWORK   = 32;   // worker blocks, all on one XCD
constexpr int RING    = 4;
constexpr int NSEL    = 256;  // selector grid

// ---------------------------------------------------------------- clear ws
__global__ void k_clear(unsigned int* __restrict__ p, int n) {
    int i = blockIdx.x * blockDim.x + threadIdx.x;
    if (i < n) p[i] = 0u;
}

// ---------------------------------------------------------------- phase 1
__global__ __launch_bounds__(512, 1) void k_phase1(
    const float* __restrict__ x,        // [T][192]
    const float* __restrict__ W_in,     // [H][192]
    const float* __restrict__ V,        // [H][H]
    const float* __restrict__ b_rec,    // [H]
    const float* __restrict__ alpha_h_p,
    const float* __restrict__ beta_h_p,
    unsigned long long* __restrict__ mbox,  // [RING][32 cons][32 prod] u64
    unsigned int* __restrict__ sel,     // [0..7]=per-XCD counters, [8]=winner
    uint2* __restrict__ raster)         // [T][32] tagged words
{
    const int tid = threadIdx.x;
    __shared__ unsigned int sh_rank, sh_win;
    __shared__ unsigned long long combine[2];   // low32 bits | count<<32

    unsigned int xcd;
    asm("s_getreg_b32 %0, hwreg(HW_REG_XCC_ID)" : "=s"(xcd));
    xcd &= 7u;

    if (tid == 0) {
        combine[0] = 0ull; combine[1] = 0ull;
        unsigned int r = __hip_atomic_fetch_add(&sel[xcd], 1u,
                             __ATOMIC_RELAXED, __HIP_MEMORY_SCOPE_AGENT);
        sh_rank = r;
        if (r == NWORK - 1) {              // 32nd block of this XCD: try to win
            unsigned int exp0 = 0u;
            __hip_atomic_compare_exchange_strong(&sel[8], &exp0, xcd + 1u,
                __ATOMIC_RELEASE, __ATOMIC_RELAXED, __HIP_MEMORY_SCOPE_AGENT);
        }
        unsigned int wv;
        do {
            wv = __hip_atomic_load(&sel[8], __ATOMIC_ACQUIRE,
                                   __HIP_MEMORY_SCOPE_AGENT);
        } while (wv == 0u);
        sh_win = wv;
    }
    __syncthreads();
    if (sh_win != xcd + 1u || sh_rank >= (unsigned)NWORK) return;  // not worker
    const int me = (int)sh_rank;

    const int w  = tid >> 6;          // wave 0..7
    const int l  = tid & 63;
    const int r_local = l >> 4;       // 0..3 row within wave
    const int cg      = l & 15;       // column group: cols cg*64..+63
    const int row = (me << 5) + (w << 2) + r_local;

    // ---- V fragment: 64 consecutive columns in VGPRs ----
    float4 vfrag[16];
    {
        const float4* vp = (const float4*)(V + (size_t)row * H_DIM + cg * 64);
        #pragma unroll
        for (int i = 0; i < 16; ++i) vfrag[i] = vp[i];
    }
    float wfrag[12];
    {
        const float* wp = W_in + row * IN_DIM + cg * 12;
        #pragma unroll
        for (int i = 0; i < 12; ++i) wfrag[i] = wp[i];
    }
    const float b_r = b_rec[row];
    const float ah  = alpha_h_p[0];
    const float bh  = beta_h_p[0];

    const float* xptr = x + cg * 12;
    float xr[12];
    #pragma unroll
    for (int i = 0; i < 12; ++i) xr[i] = 0.0f;    // x[-1] = 0

    float syn = 0.f, mem = 0.f, prev = 0.f;   // replicated across a row's lanes

    // burn chain (kept live via asm sink) — DVFS insurance in spins
    float u0 = 1.02f, u1 = 1.03f;
    const float bc = 1.0000001f, bd = 1e-30f;

    __syncthreads();   // combine[] init visible to all worker waves

    for (int t = 0; t < T_STEPS; ++t) {
        // issue x[t] prefetch (consumed next step); overlaps the poll
        const float4* xp4 = (const float4*)xptr;
        float4 f0 = xp4[0], f1 = xp4[1], f2 = xp4[2];

        // ---- hedged poll of own sector for step t-1 flags (tag t) ----
        unsigned long long word = 0ull;
        if (t > 0) {
            const unsigned int want = (unsigned int)t;
            const unsigned long long* pa =
                &mbox[((size_t)((t - 1) & (RING - 1)) * NWORK + me) * NWORK + (l & 31)];
            unsigned long long vv;
            asm volatile("global_load_dwordx2 %0, %1, off sc0\n\t"
                         "s_waitcnt vmcnt(0)"
                         : "=&v"(vv) : "v"(pa) : "memory");
            bool ok = (((unsigned int)(vv >> 16) & 0xffffu) == want) &&
                      ((unsigned int)(vv >> 48) == want);
            int spins = 0;
            while (__any(!ok)) {
                if (!ok) {
                    if (++spins <= 6) {        // fast path: shared-XCD L2
                        asm volatile("global_load_dwordx2 %0, %1, off sc0\n\t"
                                     "s_waitcnt vmcnt(0)"
                                     : "=&v"(vv) : "v"(pa) : "memory");
                    } else {                   // guaranteed path: LLC
                        vv = __hip_atomic_load(pa, __ATOMIC_RELAXED,
                                               __HIP_MEMORY_SCOPE_AGENT);
                    }
                    ok = (((unsigned int)(vv >> 16) & 0xffffu) == want) &&
                         ((unsigned int)(vv >> 48) == want);
                }
                u0 = fmaf(u0, bc, bd); u1 = fmaf(u1, bc, bd);   // burn
            }
            word = vv;
        }
        // distribute: lane needs producer words 2cg, 2cg+1 (cols cg*64..+63)
        unsigned long long p0 = __shfl(word, 2 * cg, 64);
        unsigned long long p1 = __shfl(word, 2 * cg + 1, 64);
        unsigned int b0 = ((unsigned int)p0 & 0xffffu)
                        | (((unsigned int)(p0 >> 32) & 0xffffu) << 16);
        unsigned int b1 = ((unsigned int)p1 & 0xffffu)
                        | (((unsigned int)(p1 >> 32) & 0xffffu) << 16);

        // ---- V @ S_{t-1} over my 64 columns (two parallel FMA chains) ----
        float a0 = 0.f, a1 = 0.f;
        #pragma unroll
        for (int i = 0; i < 8; ++i) {
            a0 = fmaf((float)((b0 >> (4 * i + 0)) & 1u), vfrag[i].x, a0);
            a0 = fmaf((float)((b0 >> (4 * i + 1)) & 1u), vfrag[i].y, a0);
            a0 = fmaf((float)((b0 >> (4 * i + 2)) & 1u), vfrag[i].z, a0);
            a0 = fmaf((float)((b0 >> (4 * i + 3)) & 1u), vfrag[i].w, a0);
            a1 = fmaf((float)((b1 >> (4 * i + 0)) & 1u), vfrag[8 + i].x, a1);
            a1 = fmaf((float)((b1 >> (4 * i + 1)) & 1u), vfrag[8 + i].y, a1);
            a1 = fmaf((float)((b1 >> (4 * i + 2)) & 1u), vfrag[8 + i].z, a1);
            a1 = fmaf((float)((b1 >> (4 * i + 3)) & 1u), vfrag[8 + i].w, a1);
        }
        // + W_in @ x[t-1] over my 12 k's
        #pragma unroll
        for (int i = 0; i < 12; ++i) a0 = fmaf(wfrag[i], xr[i], a0);
        float acc = a0 + a1;

        // reduce across the row's 16 lanes
        #pragma unroll
        for (int m = 1; m < 16; m <<= 1) acc += __shfl_xor(acc, m, 64);

        // state update (identical across the row's 16 lanes)
        float cur = acc + b_r;
        syn = fmaf(ah, syn, cur);
        mem = fmaf(bh, mem, syn) * (1.0f - prev);   // zero-reset, prev spike
        float spk = (mem > 1.0f) ? 1.0f : 0.0f;
        prev = spk;

        // ---- combine: ballot -> lane0 nibble -> LDS u64 add ----
        const int wsl = t & 1;
        unsigned long long bal = __ballot(spk > 0.5f);
        unsigned int isLast = 0u, bitsAll = 0u;
        if (l == 0) {
            unsigned int nib = (unsigned int)(bal & 1ull)
                             | ((unsigned int)((bal >> 16) & 1ull) << 1)
                             | ((unsigned int)((bal >> 32) & 1ull) << 2)
                             | ((unsigned int)((bal >> 48) & 1ull) << 3);
            unsigned long long add =
                (1ull << 32) | ((unsigned long long)nib << (4 * w));
            unsigned long long old = __hip_atomic_fetch_add(&combine[wsl], add,
                    __ATOMIC_RELAXED, __HIP_MEMORY_SCOPE_WORKGROUP);
            unsigned long long nv = old + add;
            if ((nv >> 32) == 8ull) { isLast = 1u; bitsAll = (unsigned int)nv; }
        }
        isLast = __shfl(isLast, 0, 64);
        if (isLast) {
            unsigned int bits = __shfl(bitsAll, 0, 64);
            unsigned int want = (unsigned int)(t + 1);
            unsigned int w0t = (want << 16) | (bits & 0xffffu);
            unsigned int w1t = (want << 16) | (bits >> 16);
            unsigned long long pack =
                (unsigned long long)w0t | ((unsigned long long)w1t << 32);
            if (l == 0) combine[wsl] = 0ull;          // re-arm for t+2
            asm volatile("s_waitcnt lgkmcnt(0)" ::: "memory");  // reset committed
            if (l < NWORK) {
                unsigned long long* ps =
                    &mbox[((size_t)(t & (RING - 1)) * NWORK + l) * NWORK + me];
                // fast path: home-L2 visibility
                asm volatile("global_store_dwordx2 %0, %1, off sc0"
                             :: "v"(ps), "v"(pack) : "memory");
                // guaranteed path: LLC visibility (same value -> benign)
                __hip_atomic_store(ps, pack, __ATOMIC_RELAXED,
                                   __HIP_MEMORY_SCOPE_AGENT);
            }
            if (l == 0) raster[(size_t)t * NWORK + me] = make_uint2(w0t, w1t);
        }

        #pragma unroll
        for (int i = 0; i < 4; ++i) {
            xr[i]     = (&f0.x)[i];
            xr[4 + i] = (&f1.x)[i];
            xr[8 + i] = (&f2.x)[i];
        }
        xptr += IN_DIM;
    }
    asm volatile("" :: "v"(u0), "v"(u1));   // keep burn chain alive
}

// ---------------------------------------------------------------- phase 2A
// R[t][rr] = W_out[rr] . S_{t-1}  (rr = h*2+o, 10 rows). W_out staged in LDS
// with pad (stride 1033) to break row-bank conflicts.
__global__ __launch_bounds__(256, 1) void k_readout_mm(
    const uint2* __restrict__ raster,  // [T][32] tagged words
    const float* __restrict__ W_out,   // [10][1024]
    float* __restrict__ R)             // [T][10]
{
    __shared__ float wlds[10 * 1033];
    for (int i = threadIdx.x; i < 10 * 1024; i += 256) {
        int r = i >> 10, c = i & 1023;
        wlds[r * 1033 + c] = W_out[i];
    }
    __syncthreads();

    int tid = threadIdx.x;
    if (tid >= 250) return;
    int tl = tid / 10, rowr = tid - tl * 10;
    int t = blockIdx.x * 25 + tl;
    if (t >= T_STEPS) return;

    float acc = 0.f;
    if (t > 0) {
        const uint2* wp = raster + (size_t)(t - 1) * NWORK;
        const float* wr = &wlds[rowr * 1033];
        for (int ww = 0; ww < NWORK; ++ww) {
            uint2 v = wp[ww];
            unsigned int bits = (v.x & 0xffffu) | ((v.y & 0xffffu) << 16);
            const float* wb = wr + ww * 32;
            #pragma unroll
            for (int j = 0; j < 32; ++j)
                acc = fmaf((float)((bits >> j) & 1u), wb[j], acc);
        }
    }
    R[t * 10 + rowr] = acc;
}

// ---------------------------------------------------------------- phase 2B
__global__ void k_scan(const float* __restrict__ R,
                       const float* __restrict__ alpha_r,
                       const float* __restrict__ beta_r,
                       float* __restrict__ memr_all)   // [T][10]
{
    int lane = threadIdx.x;
    bool act = lane < 10;
    float a = act ? alpha_r[lane >> 1] : 0.f;
    float b = act ? beta_r[lane >> 1] : 0.f;
    float syn = 0.f, mem = 0.f;
    constexpr int PF = 8;
    float buf[PF];
    #pragma unroll
    for (int i = 0; i < PF; ++i) buf[i] = act ? R[i * 10 + lane] : 0.f;

    for (int tb = 0; tb < T_STEPS; tb += PF) {
        #pragma unroll
        for (int i = 0; i < PF; ++i) {
            int t = tb + i;
            syn = fmaf(a, syn, buf[i]);
            mem = fmaf(b, mem, syn);
            if (act) memr_all[t * 10 + lane] = mem;
            int tn = t + PF;
            buf[i] = (act && tn < T_STEPS) ? R[tn * 10 + lane] : 0.f;
        }
    }
}

// ---------------------------------------------------------------- phase 2C
__global__ void k_mean(const float* __restrict__ memr_all, float* __restrict__ out) {
    int g = blockIdx.x * blockDim.x + threadIdx.x;
    if (g >= T_STEPS * 2) return;
    int t = g >> 1, o = g & 1;
    const float* m = memr_all + t * 10 + o;
    out[g] = 0.2f * (m[0] + m[2] + m[4] + m[6] + m[8]);
}

// ---------------------------------------------------------------- launch
extern "C" void kernel_launch(void* const* d_in, const int* in_sizes, int n_in,
                              void* d_out, int out_size, void* d_ws, size_t ws_size,
                              hipStream_t stream) {
    (void)in_sizes; (void)n_in; (void)out_size; (void)ws_size;
    const float* x       = (const float*)d_in[0];
    const float* W_in    = (const float*)d_in[1];
    const float* V       = (const float*)d_in[2];
    const float* b_rec   = (const float*)d_in[3];
    const float* W_out   = (const float*)d_in[4];
    const float* alpha_h = (const float*)d_in[5];
    const float* beta_h  = (const float*)d_in[6];
    const float* alpha_r = (const float*)d_in[7];
    const float* beta_r  = (const float*)d_in[8];
    float* out = (float*)d_out;

    char* wsb = (char*)d_ws;
    unsigned long long* mbox = (unsigned long long*)wsb;       // 32 KB
    unsigned int* selp = (unsigned int*)(wsb + RING * NWORK * NWORK * 8); // 64 B
    uint2* raster  = (uint2*)(wsb + RING * NWORK * NWORK * 8 + 64);      // 2 MB
    float* Rbuf    = (float*)(wsb + RING * NWORK * NWORK * 8 + 64
                              + (size_t)T_STEPS * NWORK * 8);            // 320 KB
    float* memr_all = Rbuf + (size_t)T_STEPS * 10;                       // 320 KB

    int nclr = RING * NWORK * NWORK * 2 + 16;   // mbox + sel, in u32s
    k_clear<<<(nclr + 255) / 256, 256, 0, stream>>>((unsigned int*)mbox, nclr);
    k_phase1<<<NSEL, 512, 0, stream>>>(x, W_in, V, b_rec, alpha_h, beta_h,
                                       mbox, selp, raster);
    k_readout_mm<<<(T_STEPS + 24) / 25, 256, 0, stream>>>(raster, W_out, Rbuf);
    k_scan<<<1, 64, 0, stream>>>(Rbuf, alpha_r, beta_r, memr_all);
    k_mean<<<(T_STEPS * 2 + 255) / 256, 256, 0, stream>>>(memr_all, out);
}

// Round 10
// 26533.148 us; speedup vs baseline: 1.0085x; 1.0085x over previous
//
#include <hip/hip_runtime.h>
#include <hip/hip_bf16.h>

// bigRSNN: T=8192 strictly-serial spiking RNN.
//
// Phase 1: 32 blocks x 512 threads (8 waves), one block per 32 neuron rows.
// Exchange: push-mailboxes in ws. Producer's last-arriving wave (LDS u64
// combiner) scatter-stores a tagged 8-B flag {(t+1)<<16|lo16,(t+1)<<16|hi16}
// into all 32 consumers' private 256-B sectors with one agent-scope atomic
// store (LLC-visible; the ONLY protocol proven coherent on this part: r7's
// sc0-only spin hung on stale XCD-L2, r6/r8's agent atomics worked).
// Consumers: all 8 waves poll their OWN sector with a COMPILER-BUILT
// pipelined rotation — 8 relaxed agent atomic loads in flight into named
// registers; SIInsertWaitcnts emits precise vmcnt(N) waits so each check
// waits only for its own load. Sampling period ~= L/8 instead of L, so
// detection ~= store-commit + L + L/8 (r6's serial spin paid ~2L + handoff).
// No inline-asm loads (r9's hang: missing early-clobber let the load
// clobber its own address register). No barriers, no sync wave, no LDS
// handoff in the step loop. RING=4 slots (publish at t+4 happens-after all
// reads at t+1 via the global all-waves dependency chain).
// Phase 2: readout GEMM over the tagged raster + 10 IIR scans + head mean.

constexpr int T_STEPS = 8192;
constexpr int IN_DIM  = 192;
constexpr int H_DIM   = 1024;
constexpr int NBLK    = 32;
constexpr int RING    = 4;

#define LOADP() __hip_atomic_load(pa, __ATOMIC_RELAXED, __HIP_MEMORY_SCOPE_AGENT)
#define GOOD(v) ((((unsigned int)((v) >> 16) & 0xffffu) == want) && \
                 ((unsigned int)((v) >> 48) == want))
#define POLL_STEP(ri) \
    if (!ok && GOOD(ri)) { word = ri; ok = true; } \
    if (__all(ok)) break; \
    ri = LOADP();

// ---------------------------------------------------------------- clear ws
__global__ void k_clear(unsigned int* __restrict__ p, int n) {
    int i = blockIdx.x * blockDim.x + threadIdx.x;
    if (i < n) p[i] = 0u;
}

// ---------------------------------------------------------------- phase 1
__global__ __launch_bounds__(512, 1) void k_phase1(
    const float* __restrict__ x,        // [T][192]
    const float* __restrict__ W_in,     // [H][192]
    const float* __restrict__ V,        // [H][H]
    const float* __restrict__ b_rec,    // [H]
    const float* __restrict__ alpha_h_p,
    const float* __restrict__ beta_h_p,
    unsigned long long* __restrict__ mbox,  // [RING][32 cons][32 prod] u64
    uint2* __restrict__ raster)         // [T][32] tagged words
{
    const int tid = threadIdx.x;
    const int blk = blockIdx.x;       // 0..31
    const int w   = tid >> 6;         // wave 0..7
    const int l   = tid & 63;
    const int r_local = l >> 4;       // 0..3 row within wave
    const int cg      = l & 15;       // column group: cols cg*64..+63
    const int row = (blk << 5) + (w << 2) + r_local;

    __shared__ unsigned long long combine[2];   // low32 bits | count<<32
    if (tid == 0) { combine[0] = 0ull; combine[1] = 0ull; }

    // ---- V fragment: 64 consecutive columns in VGPRs ----
    float4 vfrag[16];
    {
        const float4* vp = (const float4*)(V + (size_t)row * H_DIM + cg * 64);
        #pragma unroll
        for (int i = 0; i < 16; ++i) vfrag[i] = vp[i];
    }
    float wfrag[12];
    {
        const float* wp = W_in + row * IN_DIM + cg * 12;
        #pragma unroll
        for (int i = 0; i < 12; ++i) wfrag[i] = wp[i];
    }
    const float b_r = b_rec[row];
    const float ah  = alpha_h_p[0];
    const float bh  = beta_h_p[0];

    float syn = 0.f, mem = 0.f, prev = 0.f;   // replicated across a row's lanes

    // burn chain (kept live via asm sink): DVFS insurance inside spins
    float u0 = 1.02f, u1 = 1.03f;
    const float bc = 1.0000001f, bd = 1e-30f;

    __syncthreads();   // combine[] init visible to all waves

    for (int t = 0; t < T_STEPS; ++t) {
        // ---- x[t-1] row: issue loads BEFORE the poll (latency hides there) ----
        float4 f0 = make_float4(0.f, 0.f, 0.f, 0.f), f1 = f0, f2 = f0;
        if (t > 0) {
            const float4* xp4 = (const float4*)(x + (size_t)(t - 1) * IN_DIM + cg * 12);
            f0 = xp4[0]; f1 = xp4[1]; f2 = xp4[2];
        }

        // ---- pipelined poll of own sector for step t-1 flags (tag t) ----
        unsigned long long word = 0ull;
        if (t > 0) {
            const unsigned int want = (unsigned int)t;
            const unsigned long long* pa =
                &mbox[((size_t)((t - 1) & (RING - 1)) * NBLK + blk) * NBLK + (l & 31)];
            bool ok = false;
            unsigned long long r0 = LOADP(), r1 = LOADP(), r2 = LOADP(),
                               r3 = LOADP(), r4 = LOADP(), r5 = LOADP(),
                               r6 = LOADP(), r7 = LOADP();
            for (;;) {
                POLL_STEP(r0)
                POLL_STEP(r1)
                POLL_STEP(r2)
                POLL_STEP(r3)
                POLL_STEP(r4)
                POLL_STEP(r5)
                POLL_STEP(r6)
                POLL_STEP(r7)
                u0 = fmaf(u0, bc, bd); u1 = fmaf(u1, bc, bd);   // burn
            }
        }
        // distribute: lane needs producer words 2cg, 2cg+1 (cols cg*64..+63)
        unsigned long long p0 = __shfl(word, 2 * cg, 64);
        unsigned long long p1 = __shfl(word, 2 * cg + 1, 64);
        unsigned int b0 = ((unsigned int)p0 & 0xffffu)
                        | (((unsigned int)(p0 >> 32) & 0xffffu) << 16);
        unsigned int b1 = ((unsigned int)p1 & 0xffffu)
                        | (((unsigned int)(p1 >> 32) & 0xffffu) << 16);

        // ---- V @ S_{t-1} over my 64 columns (two parallel FMA chains) ----
        float a0 = 0.f, a1 = 0.f;
        #pragma unroll
        for (int i = 0; i < 8; ++i) {
            a0 = fmaf((float)((b0 >> (4 * i + 0)) & 1u), vfrag[i].x, a0);
            a0 = fmaf((float)((b0 >> (4 * i + 1)) & 1u), vfrag[i].y, a0);
            a0 = fmaf((float)((b0 >> (4 * i + 2)) & 1u), vfrag[i].z, a0);
            a0 = fmaf((float)((b0 >> (4 * i + 3)) & 1u), vfrag[i].w, a0);
            a1 = fmaf((float)((b1 >> (4 * i + 0)) & 1u), vfrag[8 + i].x, a1);
            a1 = fmaf((float)((b1 >> (4 * i + 1)) & 1u), vfrag[8 + i].y, a1);
            a1 = fmaf((float)((b1 >> (4 * i + 2)) & 1u), vfrag[8 + i].z, a1);
            a1 = fmaf((float)((b1 >> (4 * i + 3)) & 1u), vfrag[8 + i].w, a1);
        }
        // + W_in @ x[t-1] over my 12 k's
        #pragma unroll
        for (int i = 0; i < 4; ++i) {
            a0 = fmaf(wfrag[i],     (&f0.x)[i], a0);
            a0 = fmaf(wfrag[4 + i], (&f1.x)[i], a0);
            a0 = fmaf(wfrag[8 + i], (&f2.x)[i], a0);
        }
        float acc = a0 + a1;

        // reduce across the row's 16 lanes
        #pragma unroll
        for (int m = 1; m < 16; m <<= 1) acc += __shfl_xor(acc, m, 64);

        // state update (identical across the row's 16 lanes)
        float cur = acc + b_r;
        syn = fmaf(ah, syn, cur);
        mem = fmaf(bh, mem, syn) * (1.0f - prev);   // zero-reset, prev spike
        float spk = (mem > 1.0f) ? 1.0f : 0.0f;
        prev = spk;

        // ---- combine: ballot -> lane0 nibble -> LDS u64 add ----
        const int wsl = t & 1;
        unsigned long long bal = __ballot(spk > 0.5f);
        unsigned int isLast = 0u, bitsAll = 0u;
        if (l == 0) {
            unsigned int nib = (unsigned int)(bal & 1ull)
                             | ((unsigned int)((bal >> 16) & 1ull) << 1)
                             | ((unsigned int)((bal >> 32) & 1ull) << 2)
                             | ((unsigned int)((bal >> 48) & 1ull) << 3);
            unsigned long long add =
                (1ull << 32) | ((unsigned long long)nib << (4 * w));
            unsigned long long old = __hip_atomic_fetch_add(&combine[wsl], add,
                    __ATOMIC_RELAXED, __HIP_MEMORY_SCOPE_WORKGROUP);
            unsigned long long nv = old + add;
            if ((nv >> 32) == 8ull) { isLast = 1u; bitsAll = (unsigned int)nv; }
        }
        isLast = __shfl(isLast, 0, 64);
        if (isLast) {
            unsigned int bits = __shfl(bitsAll, 0, 64);
            unsigned int want = (unsigned int)(t + 1);
            unsigned int w0t = (want << 16) | (bits & 0xffffu);
            unsigned int w1t = (want << 16) | (bits >> 16);
            unsigned long long pack =
                (unsigned long long)w0t | ((unsigned long long)w1t << 32);
            if (l == 0) combine[wsl] = 0ull;          // re-arm for t+2
            asm volatile("s_waitcnt lgkmcnt(0)" ::: "memory");  // reset committed
            __builtin_amdgcn_sched_barrier(0);
            if (l < NBLK) {
                unsigned long long* ps =
                    &mbox[((size_t)(t & (RING - 1)) * NBLK + l) * NBLK + blk];
                __hip_atomic_store(ps, pack, __ATOMIC_RELAXED,
                                   __HIP_MEMORY_SCOPE_AGENT);
            }
            if (l == 0) raster[(size_t)t * NBLK + blk] = make_uint2(w0t, w1t);
        }
    }
    asm volatile("" :: "v"(u0), "v"(u1));   // keep burn chain alive
}

// ---------------------------------------------------------------- phase 2A
// R[t][rr] = W_out[rr] . S_{t-1}  (rr = h*2+o, 10 rows). W_out staged in LDS
// with pad (stride 1033) to break row-bank conflicts.
__global__ __launch_bounds__(256, 1) void k_readout_mm(
    const uint2* __restrict__ raster,  // [T][32] tagged words
    const float* __restrict__ W_out,   // [10][1024]
    float* __restrict__ R)             // [T][10]
{
    __shared__ float wlds[10 * 1033];
    for (int i = threadIdx.x; i < 10 * 1024; i += 256) {
        int r = i >> 10, c = i & 1023;
        wlds[r * 1033 + c] = W_out[i];
    }
    __syncthreads();

    int tid = threadIdx.x;
    if (tid >= 250) return;
    int tl = tid / 10, rowr = tid - tl * 10;
    int t = blockIdx.x * 25 + tl;
    if (t >= T_STEPS) return;

    float acc = 0.f;
    if (t > 0) {
        const uint2* wp = raster + (size_t)(t - 1) * NBLK;
        const float* wr = &wlds[rowr * 1033];
        for (int ww = 0; ww < NBLK; ++ww) {
            uint2 v = wp[ww];
            unsigned int bits = (v.x & 0xffffu) | ((v.y & 0xffffu) << 16);
            const float* wb = wr + ww * 32;
            #pragma unroll
            for (int j = 0; j < 32; ++j)
                acc = fmaf((float)((bits >> j) & 1u), wb[j], acc);
        }
    }
    R[t * 10 + rowr] = acc;
}

// ---------------------------------------------------------------- phase 2B
__global__ void k_scan(const float* __restrict__ R,
                       const float* __restrict__ alpha_r,
                       const float* __restrict__ beta_r,
                       float* __restrict__ memr_all)   // [T][10]
{
    int lane = threadIdx.x;
    bool act = lane < 10;
    float a = act ? alpha_r[lane >> 1] : 0.f;
    float b = act ? beta_r[lane >> 1] : 0.f;
    float syn = 0.f, mem = 0.f;
    constexpr int PF = 8;
    float buf[PF];
    #pragma unroll
    for (int i = 0; i < PF; ++i) buf[i] = act ? R[i * 10 + lane] : 0.f;

    for (int tb = 0; tb < T_STEPS; tb += PF) {
        #pragma unroll
        for (int i = 0; i < PF; ++i) {
            int t = tb + i;
            syn = fmaf(a, syn, buf[i]);
            mem = fmaf(b, mem, syn);
            if (act) memr_all[t * 10 + lane] = mem;
            int tn = t + PF;
            buf[i] = (act && tn < T_STEPS) ? R[tn * 10 + lane] : 0.f;
        }
    }
}

// ---------------------------------------------------------------- phase 2C
__global__ void k_mean(const float* __restrict__ memr_all, float* __restrict__ out) {
    int g = blockIdx.x * blockDim.x + threadIdx.x;
    if (g >= T_STEPS * 2) return;
    int t = g >> 1, o = g & 1;
    const float* m = memr_all + t * 10 + o;
    out[g] = 0.2f * (m[0] + m[2] + m[4] + m[6] + m[8]);
}

// ---------------------------------------------------------------- launch
extern "C" void kernel_launch(void* const* d_in, const int* in_sizes, int n_in,
                              void* d_out, int out_size, void* d_ws, size_t ws_size,
                              hipStream_t stream) {
    (void)in_sizes; (void)n_in; (void)out_size; (void)ws_size;
    const float* x       = (const float*)d_in[0];
    const float* W_in    = (const float*)d_in[1];
    const float* V       = (const float*)d_in[2];
    const float* b_rec   = (const float*)d_in[3];
    const float* W_out   = (const float*)d_in[4];
    const float* alpha_h = (const float*)d_in[5];
    const float* beta_h  = (const float*)d_in[6];
    const float* alpha_r = (const float*)d_in[7];
    const float* beta_r  = (const float*)d_in[8];
    float* out = (float*)d_out;

    char* wsb = (char*)d_ws;
    unsigned long long* mbox = (unsigned long long*)wsb;          // 32 KB
    uint2* raster  = (uint2*)(wsb + RING * NBLK * NBLK * 8);      // 2 MB
    float* Rbuf    = (float*)(wsb + RING * NBLK * NBLK * 8
                              + (size_t)T_STEPS * NBLK * 8);      // 320 KB
    float* memr_all = Rbuf + (size_t)T_STEPS * 10;                // 320 KB

    int nclr = RING * NBLK * NBLK * 2;   // mailbox region in u32s
    k_clear<<<(nclr + 255) / 256, 256, 0, stream>>>((unsigned int*)mbox, nclr);
    k_phase1<<<NBLK, 512, 0, stream>>>(x, W_in, V, b_rec, alpha_h, beta_h,
                                       mbox, raster);
    k_readout_mm<<<(T_STEPS + 24) / 25, 256, 0, stream>>>(raster, W_out, Rbuf);
    k_scan<<<1, 64, 0, stream>>>(Rbuf, alpha_r, beta_r, memr_all);
    k_mean<<<(T_STEPS * 2 + 255) / 256, 256, 0, stream>>>(memr_all, out);
}

// Round 11
// 19846.884 us; speedup vs baseline: 1.3483x; 1.3369x over previous
//
#include <hip/hip_runtime.h>
#include <hip/hip_bf16.h>

// bigRSNN: T=8192 strictly-serial spiking RNN.
//
// Phase 1: 256 blocks x 576 threads.
//   Blocks 0..31  = WORKERS (r6 structure, best so far): waves 0..7 compute
//     32 rows (4/wave, 16 lanes/row, 64 V-cols/lane in VGPRs); wave 8 = sync
//     wave polling the block's push-mailbox sector with a DEPTH-4 pipelined
//     rotation (4 relaxed agent atomic loads in flight -> sampling period
//     ~L/4); LDS ring handoff + release/acquire seq counters; last-arriving
//     compute wave (LDS u64 combiner) scatter-stores the tagged 8-B flag to
//     all consumers' sectors (agent atomic store, the only proven-coherent
//     path). No barriers in the step loop. RING=4.
//   Blocks 32..255 = BURN blocks: FP32-FMA power virus to hold DVFS clocks
//     up (r1-r10 all showed VALUBusy ~5% and step time ~2x the cycle-count
//     arithmetic; slow rocprof replicas ran 3x longer at identical counters
//     => low-clock state). Each polls doneFlag[blk&31] every ~768 FMAs and
//     exits when its worker finishes. Workers run s_setprio(1) so burners
//     lose issue arbitration if ever co-resident.
// Phase 2: readout GEMM over the tagged raster + 10 IIR scans + head mean.

constexpr int T_STEPS = 8192;
constexpr int IN_DIM  = 192;
constexpr int H_DIM   = 1024;
constexpr int NBLK    = 32;
constexpr int RING    = 4;
constexpr int NGRID   = 256;

#define LOADP() __hip_atomic_load(pa, __ATOMIC_RELAXED, __HIP_MEMORY_SCOPE_AGENT)
#define GOOD(v) ((((unsigned int)((v) >> 16) & 0xffffu) == want) && \
                 ((unsigned int)((v) >> 48) == want))
#define POLL_STEP(ri) \
    if (!ok && GOOD(ri)) { word = ri; ok = true; } \
    if (__all(ok)) break; \
    ri = LOADP();

// ---------------------------------------------------------------- clear ws
__global__ void k_clear(unsigned int* __restrict__ p, int n) {
    int i = blockIdx.x * blockDim.x + threadIdx.x;
    if (i < n) p[i] = 0u;
}

// ---------------------------------------------------------------- phase 1
__global__ __launch_bounds__(576, 1) void k_phase1(
    const float* __restrict__ x,        // [T][192]
    const float* __restrict__ W_in,     // [H][192]
    const float* __restrict__ V,        // [H][H]
    const float* __restrict__ b_rec,    // [H]
    const float* __restrict__ alpha_h_p,
    const float* __restrict__ beta_h_p,
    unsigned long long* __restrict__ mbox,  // [RING][32 cons][32 prod] u64
    unsigned int* __restrict__ doneFlag,    // [32] padded to 64B sectors
    uint2* __restrict__ raster)         // [T][32] tagged words
{
    const int tid = threadIdx.x;
    const int blk = blockIdx.x;
    const float bc = 1.0000001f, bd = 1e-30f;

    if (blk >= NBLK) {
        // ---------------- burn block: clock-pinning power virus ----------------
        __shared__ volatile int exitf;
        if (tid == 0) exitf = 0;
        __syncthreads();
        float u0 = 1.02f, u1 = 1.03f, u2 = 1.05f, u3 = 1.07f;
        const unsigned int* df = &doneFlag[(blk & 31) << 4];
        for (;;) {
            #pragma unroll 8
            for (int i = 0; i < 192; ++i) {
                u0 = fmaf(u0, bc, bd); u1 = fmaf(u1, bc, bd);
                u2 = fmaf(u2, bc, bd); u3 = fmaf(u3, bc, bd);
            }
            if (tid == 0 &&
                __hip_atomic_load(df, __ATOMIC_RELAXED, __HIP_MEMORY_SCOPE_AGENT))
                exitf = 1;
            if (exitf) break;
        }
        asm volatile("" :: "v"(u0), "v"(u1), "v"(u2), "v"(u3));
        return;
    }

    // ---------------- worker block (r6 structure) ----------------
    __builtin_amdgcn_s_setprio(1);   // beat co-resident burners at issue arb

    const int w     = tid >> 6;         // wave 0..8
    const int l     = tid & 63;
    const bool syncw = (w == 8);
    const int r_local = l >> 4;         // 0..3 row within wave
    const int cg      = l & 15;         // column group: cols cg*64..+63
    const int row   = (blk << 5) + (w << 2) + r_local;  // compute waves only

    __shared__ unsigned int       bits_lds[RING][NBLK];
    __shared__ unsigned long long combine[2];           // low32 bits|count<<32
    __shared__ unsigned long long rdyPack;              // lo=rdySync, hi=rdyOwn

    for (int i = tid; i < RING * NBLK; i += 576)
        ((unsigned int*)bits_lds)[i] = 0u;
    if (tid == 0) { combine[0] = 0ull; combine[1] = 0ull; rdyPack = 0ull; }
    unsigned int* rp = (unsigned int*)&rdyPack;   // rp[0]=sync, rp[1]=own

    float4 vfrag[16];
    float  wfrag[12];
    float  b_r = 0.f;
    if (!syncw) {
        const float4* vp = (const float4*)(V + (size_t)row * H_DIM + cg * 64);
        #pragma unroll
        for (int i = 0; i < 16; ++i) vfrag[i] = vp[i];
        const float* wp = W_in + row * IN_DIM + cg * 12;
        #pragma unroll
        for (int i = 0; i < 12; ++i) wfrag[i] = wp[i];
        b_r = b_rec[row];
    }
    const float ah = alpha_h_p[0];
    const float bh = beta_h_p[0];

    __syncthreads();   // init visible to all waves (once, outside the loop)

    float u0 = 1.02f, u1 = 1.03f;   // in-spin burn chains

    if (syncw) {
        // ---- sync wave: depth-4 pipelined mailbox poll -> LDS pump ----
        const bool act = (l < NBLK) && (l != blk);
        for (int t = 0; t < T_STEPS - 1; ++t) {
            const unsigned int want = (unsigned int)(t + 1);
            const unsigned long long* pa =
                &mbox[((size_t)(t & (RING - 1)) * NBLK + blk) * NBLK + (l & 31)];
            unsigned long long word =
                ((unsigned long long)want << 16) | ((unsigned long long)want << 48);
            bool ok = !act;
            unsigned long long r0 = LOADP(), r1 = LOADP(),
                               r2 = LOADP(), r3 = LOADP();
            for (;;) {
                POLL_STEP(r0)
                POLL_STEP(r1)
                POLL_STEP(r2)
                POLL_STEP(r3)
                u0 = fmaf(u0, bc, bd); u1 = fmaf(u1, bc, bd);   // burn
            }
            if (act)
                bits_lds[t & (RING - 1)][l] =
                    (unsigned int)(word & 0xffffull)
                    | ((unsigned int)((word >> 32) & 0xffffull) << 16);
            if (l == 0)
                __hip_atomic_store(&rp[0], (unsigned int)(t + 1),
                                   __ATOMIC_RELEASE, __HIP_MEMORY_SCOPE_WORKGROUP);
        }
    } else {
        // ---- compute waves ----
        const float* xptr = x + cg * 12;
        float xr[12];
        #pragma unroll
        for (int i = 0; i < 12; ++i) xr[i] = 0.0f;   // x[-1] = 0
        float syn = 0.f, mem = 0.f, prev = 0.f;

        for (int t = 0; t < T_STEPS; ++t) {
            // issue x[t] prefetch (consumed next step); overlaps the spin
            const float4* xp4 = (const float4*)xptr;
            float4 f0 = xp4[0], f1 = xp4[1], f2 = xp4[2];

            // acquire-spin: remote bits (rdySync>=t) and own bits (rdyOwn>=t)
            unsigned long long rv = __hip_atomic_load(&rdyPack, __ATOMIC_ACQUIRE,
                                        __HIP_MEMORY_SCOPE_WORKGROUP);
            while ((unsigned int)rv < (unsigned int)t ||
                   (unsigned int)(rv >> 32) < (unsigned int)t) {
                u0 = fmaf(u0, bc, bd); u1 = fmaf(u1, bc, bd);
                rv = __hip_atomic_load(&rdyPack, __ATOMIC_ACQUIRE,
                                       __HIP_MEMORY_SCOPE_WORKGROUP);
            }

            const int slot = (t + RING - 1) & (RING - 1);   // (t-1) & 3
            unsigned int b0 = bits_lds[slot][2 * cg];
            unsigned int b1 = bits_lds[slot][2 * cg + 1];

            // V @ S_{t-1} over my 64 columns (two parallel FMA chains)
            float a0 = 0.f, a1 = 0.f;
            #pragma unroll
            for (int i = 0; i < 8; ++i) {
                a0 = fmaf((float)((b0 >> (4 * i + 0)) & 1u), vfrag[i].x, a0);
                a0 = fmaf((float)((b0 >> (4 * i + 1)) & 1u), vfrag[i].y, a0);
                a0 = fmaf((float)((b0 >> (4 * i + 2)) & 1u), vfrag[i].z, a0);
                a0 = fmaf((float)((b0 >> (4 * i + 3)) & 1u), vfrag[i].w, a0);
                a1 = fmaf((float)((b1 >> (4 * i + 0)) & 1u), vfrag[8 + i].x, a1);
                a1 = fmaf((float)((b1 >> (4 * i + 1)) & 1u), vfrag[8 + i].y, a1);
                a1 = fmaf((float)((b1 >> (4 * i + 2)) & 1u), vfrag[8 + i].z, a1);
                a1 = fmaf((float)((b1 >> (4 * i + 3)) & 1u), vfrag[8 + i].w, a1);
            }
            // + W_in @ x[t-1] over my 12 k's
            #pragma unroll
            for (int i = 0; i < 12; ++i) a0 = fmaf(wfrag[i], xr[i], a0);
            float acc = a0 + a1;

            // reduce across the row's 16 lanes
            #pragma unroll
            for (int m = 1; m < 16; m <<= 1) acc += __shfl_xor(acc, m, 64);

            // state update (identical across the row's 16 lanes)
            float cur = acc + b_r;
            syn = fmaf(ah, syn, cur);
            mem = fmaf(bh, mem, syn) * (1.0f - prev);   // zero-reset, prev spike
            float spk = (mem > 1.0f) ? 1.0f : 0.0f;
            prev = spk;

            // combine: ballot -> lane0 packs 4-bit nibble -> LDS u64 add
            unsigned long long bal = __ballot(spk > 0.5f);
            unsigned int isLast = 0u, bitsAll = 0u;
            if (l == 0) {
                unsigned int nib = (unsigned int)(bal & 1ull)
                                 | ((unsigned int)((bal >> 16) & 1ull) << 1)
                                 | ((unsigned int)((bal >> 32) & 1ull) << 2)
                                 | ((unsigned int)((bal >> 48) & 1ull) << 3);
                unsigned long long add =
                    (1ull << 32) | ((unsigned long long)nib << (4 * w));
                unsigned long long old = __hip_atomic_fetch_add(&combine[t & 1],
                        add, __ATOMIC_RELAXED, __HIP_MEMORY_SCOPE_WORKGROUP);
                unsigned long long nv = old + add;
                if ((nv >> 32) == 8ull) { isLast = 1u; bitsAll = (unsigned int)nv; }
            }
            isLast = __shfl(isLast, 0, 64);
            if (isLast) {
                unsigned int bits = __shfl(bitsAll, 0, 64);
                unsigned int want = (unsigned int)(t + 1);
                unsigned int w0t = (want << 16) | (bits & 0xffffu);
                unsigned int w1t = (want << 16) | (bits >> 16);
                unsigned long long pack =
                    (unsigned long long)w0t | ((unsigned long long)w1t << 32);
                if (l < NBLK && l != blk) {
                    __hip_atomic_store(
                        &mbox[((size_t)(t & (RING - 1)) * NBLK + l) * NBLK + blk],
                        pack, __ATOMIC_RELAXED, __HIP_MEMORY_SCOPE_AGENT);
                }
                if (l == 0) {
                    raster[(size_t)t * NBLK + blk] = make_uint2(w0t, w1t);
                    bits_lds[t & (RING - 1)][blk] = bits;   // own bits
                    combine[t & 1] = 0ull;                  // re-arm for t+2
                    __hip_atomic_store(&rp[1], (unsigned int)(t + 1),
                                       __ATOMIC_RELEASE,
                                       __HIP_MEMORY_SCOPE_WORKGROUP);
                }
            }

            #pragma unroll
            for (int i = 0; i < 4; ++i) {
                xr[i]     = (&f0.x)[i];
                xr[4 + i] = (&f1.x)[i];
                xr[8 + i] = (&f2.x)[i];
            }
            xptr += IN_DIM;
        }
    }
    asm volatile("" :: "v"(u0), "v"(u1));   // keep burn chains alive

    // signal burners: this worker is done
    if (tid == 0)
        __hip_atomic_store(&doneFlag[blk << 4], 1u,
                           __ATOMIC_RELAXED, __HIP_MEMORY_SCOPE_AGENT);
}

// ---------------------------------------------------------------- phase 2A
// R[t][rr] = W_out[rr] . S_{t-1}  (rr = h*2+o, 10 rows). W_out staged in LDS
// with pad (stride 1033) to break row-bank conflicts.
__global__ __launch_bounds__(256, 1) void k_readout_mm(
    const uint2* __restrict__ raster,  // [T][32] tagged words
    const float* __restrict__ W_out,   // [10][1024]
    float* __restrict__ R)             // [T][10]
{
    __shared__ float wlds[10 * 1033];
    for (int i = threadIdx.x; i < 10 * 1024; i += 256) {
        int r = i >> 10, c = i & 1023;
        wlds[r * 1033 + c] = W_out[i];
    }
    __syncthreads();

    int tid = threadIdx.x;
    if (tid >= 250) return;
    int tl = tid / 10, rowr = tid - tl * 10;
    int t = blockIdx.x * 25 + tl;
    if (t >= T_STEPS) return;

    float acc = 0.f;
    if (t > 0) {
        const uint2* wp = raster + (size_t)(t - 1) * NBLK;
        const float* wr = &wlds[rowr * 1033];
        for (int ww = 0; ww < NBLK; ++ww) {
            uint2 v = wp[ww];
            unsigned int bits = (v.x & 0xffffu) | ((v.y & 0xffffu) << 16);
            const float* wb = wr + ww * 32;
            #pragma unroll
            for (int j = 0; j < 32; ++j)
                acc = fmaf((float)((bits >> j) & 1u), wb[j], acc);
        }
    }
    R[t * 10 + rowr] = acc;
}

// ---------------------------------------------------------------- phase 2B
__global__ void k_scan(const float* __restrict__ R,
                       const float* __restrict__ alpha_r,
                       const float* __restrict__ beta_r,
                       float* __restrict__ memr_all)   // [T][10]
{
    int lane = threadIdx.x;
    bool act = lane < 10;
    float a = act ? alpha_r[lane >> 1] : 0.f;
    float b = act ? beta_r[lane >> 1] : 0.f;
    float syn = 0.f, mem = 0.f;
    constexpr int PF = 8;
    float buf[PF];
    #pragma unroll
    for (int i = 0; i < PF; ++i) buf[i] = act ? R[i * 10 + lane] : 0.f;

    for (int tb = 0; tb < T_STEPS; tb += PF) {
        #pragma unroll
        for (int i = 0; i < PF; ++i) {
            int t = tb + i;
            syn = fmaf(a, syn, buf[i]);
            mem = fmaf(b, mem, syn);
            if (act) memr_all[t * 10 + lane] = mem;
            int tn = t + PF;
            buf[i] = (act && tn < T_STEPS) ? R[tn * 10 + lane] : 0.f;
        }
    }
}

// ---------------------------------------------------------------- phase 2C
__global__ void k_mean(const float* __restrict__ memr_all, float* __restrict__ out) {
    int g = blockIdx.x * blockDim.x + threadIdx.x;
    if (g >= T_STEPS * 2) return;
    int t = g >> 1, o = g & 1;
    const float* m = memr_all + t * 10 + o;
    out[g] = 0.2f * (m[0] + m[2] + m[4] + m[6] + m[8]);
}

// ---------------------------------------------------------------- launch
extern "C" void kernel_launch(void* const* d_in, const int* in_sizes, int n_in,
                              void* d_out, int out_size, void* d_ws, size_t ws_size,
                              hipStream_t stream) {
    (void)in_sizes; (void)n_in; (void)out_size; (void)ws_size;
    const float* x       = (const float*)d_in[0];
    const float* W_in    = (const float*)d_in[1];
    const float* V       = (const float*)d_in[2];
    const float* b_rec   = (const float*)d_in[3];
    const float* W_out   = (const float*)d_in[4];
    const float* alpha_h = (const float*)d_in[5];
    const float* beta_h  = (const float*)d_in[6];
    const float* alpha_r = (const float*)d_in[7];
    const float* beta_r  = (const float*)d_in[8];
    float* out = (float*)d_out;

    char* wsb = (char*)d_ws;
    unsigned long long* mbox = (unsigned long long*)wsb;              // 32 KB
    unsigned int* doneFlag = (unsigned int*)(wsb + RING * NBLK * NBLK * 8); // 2 KB
    uint2* raster  = (uint2*)(wsb + RING * NBLK * NBLK * 8 + 2048);   // 2 MB
    float* Rbuf    = (float*)(wsb + RING * NBLK * NBLK * 8 + 2048
                              + (size_t)T_STEPS * NBLK * 8);          // 320 KB
    float* memr_all = Rbuf + (size_t)T_STEPS * 10;                    // 320 KB

    int nclr = RING * NBLK * NBLK * 2 + 512;   // mbox + doneFlag, in u32s
    k_clear<<<(nclr + 255) / 256, 256, 0, stream>>>((unsigned int*)mbox, nclr);
    k_phase1<<<NGRID, 576, 0, stream>>>(x, W_in, V, b_rec, alpha_h, beta_h,
                                        mbox, doneFlag, raster);
    k_readout_mm<<<(T_STEPS + 24) / 25, 256, 0, stream>>>(raster, W_out, Rbuf);
    k_scan<<<1, 64, 0, stream>>>(Rbuf, alpha_r, beta_r, memr_all);
    k_mean<<<(T_STEPS * 2 + 255) / 256, 256, 0, stream>>>(memr_all, out);
}

// Round 12
// 17638.837 us; speedup vs baseline: 1.5170x; 1.1252x over previous
//
#include <hip/hip_runtime.h>
#include <hip/hip_bf16.h>

// bigRSNN: T=8192 strictly-serial spiking RNN.
// Phase 1: 32 blocks x 576 threads, BARRIER-FREE step loop (r6 structure,
// best measured: 17.3ms) with ONE fix: the publish/handoff sequence counters
// (rdySync, rdyOwn) are bumped with RELAXED LDS stores after an
// lgkmcnt(0)-only fence, instead of RELEASE stores. Release forced
// s_waitcnt vmcnt(0) — the publishing wave drained the fabric ACK of its 31
// agent-scope mailbox stores (+ cold raster HBM store) before its own
// block's compute waves could start the next step (~300-900cy pure
// overhead per step; also why r11's depth-4 poll regressed: its release
// waited on 3 in-flight poll loads). Mailbox flags are self-validating
// (tag+data in one 8B word), so no vmem ordering is needed; only LDS
// ordering (bits_lds + combine reset before the counter bump).
//   Waves 0..7 compute 32 rows (4/wave, 16 lanes/row, 64 V-cols/lane in
//   VGPRs); wave 8 = sync wave: serial-polls its own push-mailbox sector
//   (agent atomic loads, the only proven-coherent path), writes remote bits
//   into the LDS ring, bumps rdySync. Last-arriving compute wave (LDS u64
//   combiner) scatter-stores the tagged flag to the 31 remote sectors,
//   writes own bits, bumps rdyOwn, then writes the raster (off-path).
//   RING=4; tag monotonicity + the cross-block dependency chain bound skew.
// Phase 2: readout GEMM over the tagged raster + 10 IIR scans + head mean.

constexpr int T_STEPS = 8192;
constexpr int IN_DIM  = 192;
constexpr int H_DIM   = 1024;
constexpr int NBLK    = 32;
constexpr int RING    = 4;

// ---------------------------------------------------------------- clear ws
__global__ void k_clear(unsigned int* __restrict__ p, int n) {
    int i = blockIdx.x * blockDim.x + threadIdx.x;
    if (i < n) p[i] = 0u;
}

// ---------------------------------------------------------------- phase 1
__global__ __launch_bounds__(576, 1) void k_phase1(
    const float* __restrict__ x,        // [T][192]
    const float* __restrict__ W_in,     // [H][192]
    const float* __restrict__ V,        // [H][H]
    const float* __restrict__ b_rec,    // [H]
    const float* __restrict__ alpha_h_p,
    const float* __restrict__ beta_h_p,
    unsigned long long* __restrict__ mbox,  // [RING][32 cons][32 prod] u64
    uint2* __restrict__ raster)         // [T][32] tagged words
{
    const int tid   = threadIdx.x;
    const int blk   = blockIdx.x;        // 0..31
    const int w     = tid >> 6;          // wave 0..8
    const int l     = tid & 63;
    const bool syncw = (w == 8);
    const int r_local = l >> 4;          // 0..3 (row within wave)
    const int cg      = l & 15;          // column group: cols cg*64..+63
    const int row   = (blk << 5) + (w << 2) + r_local; // compute waves only

    __shared__ unsigned int       bits_lds[RING][NBLK]; // slot = step&3
    __shared__ unsigned long long combine[2];           // low32 bits|count<<32
    __shared__ unsigned long long rdyPack;              // lo=rdySync, hi=rdyOwn

    for (int i = tid; i < RING * NBLK; i += 576)
        ((unsigned int*)bits_lds)[i] = 0u;
    if (tid == 0) { combine[0] = 0ull; combine[1] = 0ull; rdyPack = 0ull; }

    unsigned int* rp = (unsigned int*)&rdyPack;   // rp[0]=sync, rp[1]=own

    // ---- compute-wave register state ----
    float4 vfrag[16];
    float  wfrag[12];
    float  b_r = 0.f;
    if (!syncw) {
        const float4* vp = (const float4*)(V + (size_t)row * H_DIM + cg * 64);
        #pragma unroll
        for (int i = 0; i < 16; ++i) vfrag[i] = vp[i];
        const float* wp = W_in + row * IN_DIM + cg * 12;
        #pragma unroll
        for (int i = 0; i < 12; ++i) wfrag[i] = wp[i];
        b_r = b_rec[row];
    }
    const float ah = alpha_h_p[0];
    const float bh = beta_h_p[0];

    __syncthreads();   // init visible to all waves (once, outside the loop)

    // burn-chain registers (escape via asm sink so they can't be DCE'd)
    float u0 = 1.02f, u1 = 1.03f, u2 = 1.05f, u3 = 1.07f;
    const float bc = 1.0000001f, bd = 1e-30f;

    if (syncw) {
        // ------------- sync wave: free-running mailbox -> LDS pump -------------
        const bool act = (l < NBLK) && (l != blk);
        for (int t = 0; t < T_STEPS - 1; ++t) {
            const unsigned int want = (unsigned int)(t + 1);
            const unsigned long long* p =
                &mbox[(size_t)(((t & (RING - 1)) * NBLK + blk) * NBLK) + (l & 31)];
            unsigned long long vv = act
                ? __hip_atomic_load(p, __ATOMIC_RELAXED, __HIP_MEMORY_SCOPE_AGENT)
                : (((unsigned long long)want << 16) | ((unsigned long long)want << 48));
            bool ok = (((vv >> 16) & 0xffffull) == want) && ((vv >> 48) == want);
            while (__any(!ok)) {
                if (!ok)
                    vv = __hip_atomic_load(p, __ATOMIC_RELAXED,
                                           __HIP_MEMORY_SCOPE_AGENT);
                #pragma unroll
                for (int i = 0; i < 8; ++i) {   // burn under load latency
                    u0 = fmaf(u0, bc, bd); u1 = fmaf(u1, bc, bd);
                    u2 = fmaf(u2, bc, bd); u3 = fmaf(u3, bc, bd);
                }
                ok = (((vv >> 16) & 0xffffull) == want) && ((vv >> 48) == want);
            }
            if (act)
                bits_lds[t & (RING - 1)][l] =
                    (unsigned int)(vv & 0xffffull)
                    | ((unsigned int)((vv >> 32) & 0xffffull) << 16);
            // LDS-only fence, then relaxed bump (no vmcnt drain)
            asm volatile("s_waitcnt lgkmcnt(0)" ::: "memory");
            __builtin_amdgcn_sched_barrier(0);
            if (l == 0)
                __hip_atomic_store(&rp[0], (unsigned int)(t + 1),
                                   __ATOMIC_RELAXED, __HIP_MEMORY_SCOPE_WORKGROUP);
        }
    } else {
        // ------------- compute waves -------------
        const float* xptr = x + cg * 12;
        float xr[12];
        #pragma unroll
        for (int i = 0; i < 12; ++i) xr[i] = 0.0f;   // x[-1] = 0
        float syn = 0.f, mem = 0.f, prev = 0.f;

        for (int t = 0; t < T_STEPS; ++t) {
            // issue x[t] prefetch (consumed next step); overlaps the spin
            const float4* xp4 = (const float4*)xptr;
            float4 f0 = xp4[0], f1 = xp4[1], f2 = xp4[2];

            // acquire-spin: remote bits (rdySync>=t) and own bits (rdyOwn>=t)
            unsigned long long rv = __hip_atomic_load(&rdyPack, __ATOMIC_ACQUIRE,
                                        __HIP_MEMORY_SCOPE_WORKGROUP);
            while ((unsigned int)rv < (unsigned int)t ||
                   (unsigned int)(rv >> 32) < (unsigned int)t) {
                #pragma unroll
                for (int i = 0; i < 4; ++i) {   // burn under LDS latency
                    u0 = fmaf(u0, bc, bd); u1 = fmaf(u1, bc, bd);
                    u2 = fmaf(u2, bc, bd); u3 = fmaf(u3, bc, bd);
                }
                rv = __hip_atomic_load(&rdyPack, __ATOMIC_ACQUIRE,
                                       __HIP_MEMORY_SCOPE_WORKGROUP);
            }

            const int slot = (t + RING - 1) & (RING - 1);   // (t-1) & 3
            unsigned int b0 = bits_lds[slot][2 * cg];       // cols cg*64..+31
            unsigned int b1 = bits_lds[slot][2 * cg + 1];   // cols +32..+63

            // V @ S_{t-1} over my 64 columns (two parallel FMA chains)
            float a0 = 0.f, a1 = 0.f;
            #pragma unroll
            for (int i = 0; i < 8; ++i) {
                a0 = fmaf((float)((b0 >> (4 * i + 0)) & 1u), vfrag[i].x, a0);
                a0 = fmaf((float)((b0 >> (4 * i + 1)) & 1u), vfrag[i].y, a0);
                a0 = fmaf((float)((b0 >> (4 * i + 2)) & 1u), vfrag[i].z, a0);
                a0 = fmaf((float)((b0 >> (4 * i + 3)) & 1u), vfrag[i].w, a0);
                a1 = fmaf((float)((b1 >> (4 * i + 0)) & 1u), vfrag[8 + i].x, a1);
                a1 = fmaf((float)((b1 >> (4 * i + 1)) & 1u), vfrag[8 + i].y, a1);
                a1 = fmaf((float)((b1 >> (4 * i + 2)) & 1u), vfrag[8 + i].z, a1);
                a1 = fmaf((float)((b1 >> (4 * i + 3)) & 1u), vfrag[8 + i].w, a1);
            }
            // + W_in @ x[t-1] over my 12 k's
            #pragma unroll
            for (int i = 0; i < 12; ++i) a0 = fmaf(wfrag[i], xr[i], a0);
            float acc = a0 + a1;

            // reduce across the row's 16 lanes
            #pragma unroll
            for (int m = 1; m < 16; m <<= 1) acc += __shfl_xor(acc, m, 64);

            // state update (identical across the row's 16 lanes)
            float cur = acc + b_r;
            syn = fmaf(ah, syn, cur);
            mem = fmaf(bh, mem, syn) * (1.0f - prev);   // zero-reset, prev spike
            float spk = (mem > 1.0f) ? 1.0f : 0.0f;
            prev = spk;

            // combine: ballot -> lane0 packs 4-bit nibble -> LDS u64 add
            unsigned long long bal = __ballot(spk > 0.5f);
            unsigned int isLast = 0u, bitsAll = 0u;
            if (l == 0) {
                unsigned int nib = (unsigned int)(bal & 1ull)
                                 | ((unsigned int)((bal >> 16) & 1ull) << 1)
                                 | ((unsigned int)((bal >> 32) & 1ull) << 2)
                                 | ((unsigned int)((bal >> 48) & 1ull) << 3);
                unsigned long long add =
                    (1ull << 32) | ((unsigned long long)nib << (4 * w));
                unsigned long long old = __hip_atomic_fetch_add(&combine[t & 1],
                        add, __ATOMIC_RELAXED, __HIP_MEMORY_SCOPE_WORKGROUP);
                unsigned long long nv = old + add;
                if ((nv >> 32) == 8ull) { isLast = 1u; bitsAll = (unsigned int)nv; }
            }
            isLast = __shfl(isLast, 0, 64);
            if (isLast) {
                unsigned int bits = __shfl(bitsAll, 0, 64);
                unsigned int want = (unsigned int)(t + 1);
                unsigned int w0t = (want << 16) | (bits & 0xffffu);
                unsigned int w1t = (want << 16) | (bits >> 16);
                unsigned long long pack =
                    (unsigned long long)w0t | ((unsigned long long)w1t << 32);
                // fire-and-forget: tagged flags are self-validating, no fence
                if (l < NBLK && l != blk) {
                    __hip_atomic_store(
                        &mbox[(size_t)(((t & (RING - 1)) * NBLK + l) * NBLK) + blk],
                        pack, __ATOMIC_RELAXED, __HIP_MEMORY_SCOPE_AGENT);
                }
                if (l == 0) {
                    bits_lds[t & (RING - 1)][blk] = bits;   // own bits
                    combine[t & 1] = 0ull;                  // re-arm for t+2
                    // LDS-only fence, then relaxed bump (no vmcnt drain)
                    asm volatile("s_waitcnt lgkmcnt(0)" ::: "memory");
                    __builtin_amdgcn_sched_barrier(0);
                    __hip_atomic_store(&rp[1], (unsigned int)(t + 1),
                                       __ATOMIC_RELAXED,
                                       __HIP_MEMORY_SCOPE_WORKGROUP);
                    // raster write AFTER the bump: off the critical path
                    raster[(size_t)t * NBLK + blk] = make_uint2(w0t, w1t);
                }
            }

            #pragma unroll
            for (int i = 0; i < 4; ++i) {
                xr[i]     = (&f0.x)[i];
                xr[4 + i] = (&f1.x)[i];
                xr[8 + i] = (&f2.x)[i];
            }
            xptr += IN_DIM;
        }
    }
    // keep burn chains alive (prevents DCE; negligible cost)
    asm volatile("" :: "v"(u0), "v"(u1), "v"(u2), "v"(u3));
}

// ---------------------------------------------------------------- phase 2A
// R[t][rr] = W_out[rr] . S_{t-1}  (rr = h*2+o, 10 rows). W_out staged in LDS
// with pad (stride 1033) to break row-bank conflicts.
__global__ __launch_bounds__(256, 1) void k_readout_mm(
    const uint2* __restrict__ raster,  // [T][32] tagged words
    const float* __restrict__ W_out,   // [10][1024]
    float* __restrict__ R)             // [T][10]
{
    __shared__ float wlds[10 * 1033];
    for (int i = threadIdx.x; i < 10 * 1024; i += 256) {
        int r = i >> 10, c = i & 1023;
        wlds[r * 1033 + c] = W_out[i];
    }
    __syncthreads();

    int tid = threadIdx.x;
    if (tid >= 250) return;
    int tl = tid / 10, rowr = tid - tl * 10;
    int t = blockIdx.x * 25 + tl;
    if (t >= T_STEPS) return;

    float acc = 0.f;
    if (t > 0) {
        const uint2* wp = raster + (size_t)(t - 1) * NBLK;
        const float* wr = &wlds[rowr * 1033];
        for (int ww = 0; ww < NBLK; ++ww) {
            uint2 v = wp[ww];
            unsigned int bits = (v.x & 0xffffu) | ((v.y & 0xffffu) << 16);
            const float* wb = wr + ww * 32;
            #pragma unroll
            for (int j = 0; j < 32; ++j)
                acc = fmaf((float)((bits >> j) & 1u), wb[j], acc);
        }
    }
    R[t * 10 + rowr] = acc;
}

// ---------------------------------------------------------------- phase 2B
__global__ void k_scan(const float* __restrict__ R,
                       const float* __restrict__ alpha_r,
                       const float* __restrict__ beta_r,
                       float* __restrict__ memr_all)   // [T][10]
{
    int lane = threadIdx.x;
    bool act = lane < 10;
    float a = act ? alpha_r[lane >> 1] : 0.f;
    float b = act ? beta_r[lane >> 1] : 0.f;
    float syn = 0.f, mem = 0.f;
    constexpr int PF = 8;
    float buf[PF];
    #pragma unroll
    for (int i = 0; i < PF; ++i) buf[i] = act ? R[i * 10 + lane] : 0.f;

    for (int tb = 0; tb < T_STEPS; tb += PF) {
        #pragma unroll
        for (int i = 0; i < PF; ++i) {
            int t = tb + i;
            syn = fmaf(a, syn, buf[i]);
            mem = fmaf(b, mem, syn);
            if (act) memr_all[t * 10 + lane] = mem;
            int tn = t + PF;
            buf[i] = (act && tn < T_STEPS) ? R[tn * 10 + lane] : 0.f;
        }
    }
}

// ---------------------------------------------------------------- phase 2C
__global__ void k_mean(const float* __restrict__ memr_all, float* __restrict__ out) {
    int g = blockIdx.x * blockDim.x + threadIdx.x;
    if (g >= T_STEPS * 2) return;
    int t = g >> 1, o = g & 1;
    const float* m = memr_all + t * 10 + o;
    out[g] = 0.2f * (m[0] + m[2] + m[4] + m[6] + m[8]);
}

// ---------------------------------------------------------------- launch
extern "C" void kernel_launch(void* const* d_in, const int* in_sizes, int n_in,
                              void* d_out, int out_size, void* d_ws, size_t ws_size,
                              hipStream_t stream) {
    (void)in_sizes; (void)n_in; (void)out_size; (void)ws_size;
    const float* x       = (const float*)d_in[0];
    const float* W_in    = (const float*)d_in[1];
    const float* V       = (const float*)d_in[2];
    const float* b_rec   = (const float*)d_in[3];
    const float* W_out   = (const float*)d_in[4];
    const float* alpha_h = (const float*)d_in[5];
    const float* beta_h  = (const float*)d_in[6];
    const float* alpha_r = (const float*)d_in[7];
    const float* beta_r  = (const float*)d_in[8];
    float* out = (float*)d_out;

    char* wsb = (char*)d_ws;
    unsigned long long* mbox = (unsigned long long*)wsb;   // 4*32*32*8 = 32 KB
    uint2* raster  = (uint2*)(wsb + RING * NBLK * NBLK * 8);          // 2 MB
    float* Rbuf    = (float*)(wsb + RING * NBLK * NBLK * 8
                              + (size_t)T_STEPS * NBLK * 8);          // 320 KB
    float* memr_all = Rbuf + (size_t)T_STEPS * 10;                    // 320 KB

    int nclr = RING * NBLK * NBLK * 2;   // mailbox region in u32s
    k_clear<<<(nclr + 255) / 256, 256, 0, stream>>>((unsigned int*)mbox, nclr);
    k_phase1<<<NBLK, 576, 0, stream>>>(x, W_in, V, b_rec, alpha_h, beta_h,
                                       mbox, raster);
    k_readout_mm<<<(T_STEPS + 24) / 25, 256, 0, stream>>>(raster, W_out, Rbuf);
    k_scan<<<1, 64, 0, stream>>>(Rbuf, alpha_r, beta_r, memr_all);
    k_mean<<<(T_STEPS * 2 + 255) / 256, 256, 0, stream>>>(memr_all, out);
}